// Round 1
// baseline (250.513 us; speedup 1.0000x reference)
//
#include <hip/hip_runtime.h>
#include <math.h>

#define D_MODELC 1024
#define K_HEADSC 32
#define ANCHORC 4
#define M_THETAC 4
#define H_DIMC 32
#define TOTALC 2080
#define B_SZC 4
#define L_SEQC 2048
#define NCHUNK 32
#define CHUNK_L (L_SEQC / NCHUNK)  // 64
#define INV_2PI 0.15915494309189535f
// Folded channels: theta grid is antisymmetric (theta[3-m] == -theta[m]),
// so re channels (h,m)/(h,3-m) are equal and im channels negated. We keep
// m in {0,1} only (NCH_F = 2*H*2 = 128) and fold the pair weights into wtp.
#define NCH_F 128

typedef unsigned short ushort_t;
typedef __attribute__((ext_vector_type(8))) short short8;
typedef __attribute__((ext_vector_type(4))) float f32x4;

__device__ __forceinline__ ushort_t f2bf(float f) {
  union { float f; unsigned u; } v; v.f = f;
  unsigned u = v.u;
  return (ushort_t)((u + 0x7fffu + ((u >> 16) & 1u)) >> 16);
}
__device__ __forceinline__ ushort_t f2bf_fast(float f) {
  union { float f; unsigned u; } v; v.f = f;
  return (ushort_t)((v.u + 0x8000u) >> 16);
}
__device__ __forceinline__ float bf2f(ushort_t b) {
  union { unsigned u; float f; } v; v.u = ((unsigned)b) << 16;
  return v.f;
}

// ---------------------------------------------------------------------------
// prep: fused x->bf16 cast, W_in^T, W_out^T, folded wt_pack (block-range)
// ---------------------------------------------------------------------------
__global__ __launch_bounds__(256) void prep(
    const float* __restrict__ x, const float* __restrict__ W_in,
    const float* __restrict__ W_out, const float* __restrict__ W_re,
    const float* __restrict__ W_im, const float* __restrict__ nsc,
    ushort_t* __restrict__ xb, ushort_t* __restrict__ WtI,
    ushort_t* __restrict__ WtO, ushort_t* __restrict__ wtp) {
  __shared__ float tile[32][33];
  const int bid = blockIdx.x;
  const int t = threadIdx.x;
  if (bid < 8192) {
    const int i = (bid * 256 + t) * 4;
    float4 v = *(const float4*)(x + i);
    ushort4 o = {f2bf(v.x), f2bf(v.y), f2bf(v.z), f2bf(v.w)};
    *(ushort4*)(xb + i) = o;
    return;
  }
  const float* W;
  ushort_t* Wt;
  int N, bx, by;
  if (bid < 10368) {
    const int bb = bid - 8192;
    W = W_in; Wt = WtI; N = TOTALC;
    bx = bb % 68; by = bb / 68;
  } else if (bid < 11392) {
    const int bb = bid - 10368;
    W = W_out; Wt = WtO; N = D_MODELC;
    bx = bb % 32; by = bb / 32;
  } else {
    // folded weight pack: 32 h_out x 128 folded channels
    const int i = (bid - 11392) * 256 + t;  // 0..4095
    const int h_out = i & 31;
    const int chp = i >> 5;                 // 0..127
    const bool isre = chp < 64;
    const int cc = chp & 63;
    const int hh = cc >> 1, mm = cc & 1;
    const int c1 = hh * 4 + mm;
    const int c2 = hh * 4 + (3 - mm);
    float wv;
    if (isre)
      wv = nsc[c1] * W_re[c1 * 32 + h_out] + nsc[c2] * W_re[c2 * 32 + h_out];
    else
      wv = nsc[128 + c1] * W_im[c1 * 32 + h_out] - nsc[128 + c2] * W_im[c2 * 32 + h_out];
    wtp[h_out * NCH_F + chp] = f2bf(wv);
    return;
  }
  const int K = D_MODELC;
  const int n0 = bx * 32, k0 = by * 32;
  const int tx = t & 31, ty = t >> 5;
#pragma unroll
  for (int i = 0; i < 4; i++) {
    const int kk = ty + i * 8;
    const int n = n0 + tx;
    tile[kk][tx] = (n < N) ? W[(size_t)(k0 + kk) * N + n] : 0.f;
  }
  __syncthreads();
#pragma unroll
  for (int i = 0; i < 4; i++) {
    const int nn = ty + i * 8;
    Wt[(size_t)(n0 + nn) * K + k0 + tx] = f2bf(tile[tx][nn]);
  }
}

// ---------------------------------------------------------------------------
// bf16 MFMA GEMM: C[M,Nout] = A[M,K] @ Bt[N,K]^T  (out fp32 or bf16)
// BK=64, XOR-swizzled LDS (source-side swizzle for global_load_lds).
// (unchanged this round — isolate scan-side changes)
// ---------------------------------------------------------------------------
template <bool OBF16>
__global__ __launch_bounds__(256) void gemm_bf16_bt(
    const ushort_t* __restrict__ A, const ushort_t* __restrict__ Bt,
    void* __restrict__ Cv, int M, int K, int Nout) {
  __shared__ ushort_t As[128 * 64];
  __shared__ ushort_t Bs[128 * 64];
  const int t = threadIdx.x;
  const int wave = t >> 6, lane = t & 63;
  const int m0 = blockIdx.y * 128, n0 = blockIdx.x * 128;
  const int m0w = (wave >> 1) * 64, n0w = (wave & 1) * 64;
  const int quad = lane >> 4, r16 = lane & 15;
  const int srow = lane >> 3;
  const int scol = ((lane & 7) ^ srow) * 8;

  f32x4 acc[4][4] = {};

  for (int k0 = 0; k0 < K; k0 += 64) {
    __syncthreads();
#pragma unroll
    for (int i = 0; i < 4; i++) {
      const int seg = wave * 4 + i;
      const int row = seg * 8 + srow;
      const ushort_t* gpA = A + (size_t)(m0 + row) * K + k0 + scol;
      const ushort_t* gpB = Bt + (size_t)(n0 + row) * K + k0 + scol;
      __builtin_amdgcn_global_load_lds(
          (const __attribute__((address_space(1))) void*)gpA,
          (__attribute__((address_space(3))) void*)(As + seg * 512), 16, 0, 0);
      __builtin_amdgcn_global_load_lds(
          (const __attribute__((address_space(1))) void*)gpB,
          (__attribute__((address_space(3))) void*)(Bs + seg * 512), 16, 0, 0);
    }
    __syncthreads();
#pragma unroll
    for (int kk = 0; kk < 2; kk++) {
      const int swz = ((kk * 4 + quad) ^ (r16 & 7)) * 8;
      short8 af[4], bfv[4];
#pragma unroll
      for (int i = 0; i < 4; i++)
        af[i] = *(const short8*)(As + (m0w + i * 16 + r16) * 64 + swz);
#pragma unroll
      for (int j = 0; j < 4; j++)
        bfv[j] = *(const short8*)(Bs + (n0w + j * 16 + r16) * 64 + swz);
#pragma unroll
      for (int i = 0; i < 4; i++)
#pragma unroll
        for (int j = 0; j < 4; j++)
          acc[i][j] = __builtin_amdgcn_mfma_f32_16x16x32_bf16(
              af[i], bfv[j], acc[i][j], 0, 0, 0);
    }
  }

#pragma unroll
  for (int i = 0; i < 4; i++) {
#pragma unroll
    for (int j = 0; j < 4; j++) {
      const int n = n0 + n0w + j * 16 + r16;
      if (n >= Nout) continue;
#pragma unroll
      for (int r = 0; r < 4; r++) {
        const int m = m0 + m0w + i * 16 + quad * 4 + r;
        if constexpr (OBF16) {
          ((ushort_t*)Cv)[(size_t)m * Nout + n] = f2bf(acc[i][j][r]);
        } else {
          ((float*)Cv)[(size_t)m * Nout + n] = acc[i][j][r];
        }
      }
    }
  }
}

// ---------------------------------------------------------------------------
// conv (causal depthwise k=4): unchanged this round
// ---------------------------------------------------------------------------
__global__ __launch_bounds__(256) void conv_act(
    const ushort_t* __restrict__ z, const float* __restrict__ wconv,
    const float* __restrict__ bconv, const float* __restrict__ score_scale,
    const float* __restrict__ dec_slopes, const float* __restrict__ anc_slopes,
    ushort_t* __restrict__ xv, ushort_t* __restrict__ gate,
    float* __restrict__ pw) {
  const int idx = blockIdx.x * 256 + threadIdx.x;
  if (idx >= (B_SZC * L_SEQC / 4) * (TOTALC / 4)) return;
  const int c4 = (idx % (TOTALC / 4)) * 4;
  const int bl0 = (idx / (TOTALC / 4)) * 4;  // 4 consecutive l, same b
  const int l0 = bl0 & (L_SEQC - 1);
  float4 bc = *(const float4*)(bconv + c4);
  float4 wc[4];
#pragma unroll
  for (int j = 0; j < 4; j++) wc[j] = *(const float4*)(wconv + j * TOTALC + c4);
  float zr[7][4];
#pragma unroll
  for (int r = 0; r < 7; r++) {
    const int ls = l0 - 3 + r;
    if (ls >= 0) {
      ushort4 zv = *(const ushort4*)(z + (size_t)(bl0 - 3 + r) * TOTALC + c4);
      zr[r][0] = bf2f(zv.x); zr[r][1] = bf2f(zv.y);
      zr[r][2] = bf2f(zv.z); zr[r][3] = bf2f(zv.w);
    } else {
      zr[r][0] = zr[r][1] = zr[r][2] = zr[r][3] = 0.f;
    }
  }
  float acc[4][4];
#pragma unroll
  for (int i = 0; i < 4; i++) {
    const float* b = &bc.x;
#pragma unroll
    for (int ch = 0; ch < 4; ch++) {
      float a = b[ch];
#pragma unroll
      for (int j = 0; j < 4; j++) a = fmaf(zr[i + j][ch], (&wc[j].x)[ch], a);
      acc[i][ch] = a;
    }
  }
  if (c4 < D_MODELC) {
#pragma unroll
    for (int i = 0; i < 4; i++) {
      ushort4 o = {f2bf(acc[i][0]), f2bf(acc[i][1]), f2bf(acc[i][2]), f2bf(acc[i][3])};
      *(ushort4*)(xv + (size_t)(bl0 + i) * D_MODELC + c4) = o;
    }
  } else if (c4 < 2 * D_MODELC) {
#pragma unroll
    for (int i = 0; i < 4; i++) {
      ushort4 o;
      o.x = f2bf(acc[i][0] / (1.f + __expf(-acc[i][0])));
      o.y = f2bf(acc[i][1] / (1.f + __expf(-acc[i][1])));
      o.z = f2bf(acc[i][2] / (1.f + __expf(-acc[i][2])));
      o.w = f2bf(acc[i][3] / (1.f + __expf(-acc[i][3])));
      *(ushort4*)(gate + (size_t)(bl0 + i) * D_MODELC + (c4 - D_MODELC)) = o;
    }
  } else {
    const int k0 = c4 - 2 * D_MODELC;  // 0,4,...,28 (regime uniform in group)
    float ss[4], sl[4];
#pragma unroll
    for (int i = 0; i < 4; i++) {
      const int k = k0 + i;
      ss[i] = score_scale[k];
      sl[i] = (k0 < K_HEADSC - ANCHORC)
                  ? log1pf(__expf(dec_slopes[k]))
                  : log1pf(__expf(anc_slopes[k - (K_HEADSC - ANCHORC)]));
    }
#pragma unroll
    for (int i = 0; i < 4; i++) {
      const int l = l0 + i;
      const float dist = (k0 < K_HEADSC - ANCHORC) ? (float)(L_SEQC - 1 - l) : (float)l;
      float4 o;
      float* op = &o.x;
#pragma unroll
      for (int j = 0; j < 4; j++) {
        float sv = fminf(fmaxf(ss[j] * acc[i][j], -20.f), 20.f);
        op[j] = __expf(sv) * __expf(-sl[j] * dist);
      }
      *(float4*)(pw + (size_t)(bl0 + i) * K_HEADSC + k0) = o;
    }
  }
}

// ---------------------------------------------------------------------------
// scan phase 1 (FOLDED): per (b,k,chunk) sums of pw*poly*cos/sin over the
// 128 folded channels (m in {0,1} only) + den. 128 threads/block.
// ---------------------------------------------------------------------------
__global__ __launch_bounds__(128) void scan_partial(
    const ushort_t* __restrict__ xv, const float* __restrict__ pw,
    const float* __restrict__ theta, const float* __restrict__ dlog,
    float* __restrict__ cs) {
  const int t = threadIdx.x;
  const int chunk = blockIdx.x % NCHUNK;
  const int bk = blockIdx.x / NCHUNK;
  const int k = bk % K_HEADSC;
  const int b = bk / K_HEADSC;
  __shared__ __align__(16) ushort_t xv_s[32 * 68];
  __shared__ __align__(16) float pp_s[32 * 68];
  __shared__ __align__(16) float pw_s[CHUNK_L];
  const int l0 = chunk * CHUNK_L;
  const int hld = t & 31, r0 = t >> 5;  // r0 in 0..3
  {
#pragma unroll
    for (int rr = 0; rr < 16; rr++) {
      const int l = r0 + rr * 4;
      xv_s[hld * 68 + l] = xv[(size_t)(b * L_SEQC + l0 + l) * D_MODELC + k * H_DIMC + hld];
    }
  }
  if (t < CHUNK_L)
    pw_s[t] = pw[(size_t)(b * L_SEQC + l0 + t) * K_HEADSC + k];
  const float d0 = dlog[0], d1 = dlog[1], d2 = dlog[2];
  const float mx = fmaxf(d0, fmaxf(d1, d2));
  const float e0 = __expf(d0 - mx), e1 = __expf(d1 - mx), e2 = __expf(d2 - mx);
  const float inv_sum = 1.f / (e0 + e1 + e2);
  const float w0 = e0 * inv_sum, w1 = e1 * inv_sum, w2 = e2 * inv_sum;
  const int cc = t & 63;
  const int h = cc >> 1;
  const bool is_re = (t < 64);
  const float th_rev = theta[k * 128 + h * 4 + (cc & 1)] * INV_2PI;
  __syncthreads();
  {
#pragma unroll
    for (int rr = 0; rr < 16; rr++) {
      const int l = r0 + rr * 4;
      const float xx = bf2f(xv_s[hld * 68 + l]);
      const float poly = fmaf(-w2 * xx, xx, fmaf(w1, xx, w0));
      pp_s[hld * 68 + l] = pw_s[l] * poly;
    }
  }
  __syncthreads();
  float acc = 0.f;
  const int xoff = h * 68;
  for (int l4 = 0; l4 < CHUNK_L; l4 += 4) {
    ushort4 xr = *(const ushort4*)(xv_s + xoff + l4);
    float4 pr = *(const float4*)(pp_s + xoff + l4);
    const float xs[4] = {bf2f(xr.x), bf2f(xr.y), bf2f(xr.z), bf2f(xr.w)};
    const float ps[4] = {pr.x, pr.y, pr.z, pr.w};
#pragma unroll
    for (int j = 0; j < 4; j++) {
      const float phi = xs[j] * th_rev;
      const float tr = is_re ? __builtin_amdgcn_cosf(phi) : __builtin_amdgcn_sinf(phi);
      acc = fmaf(ps[j], tr, acc);
    }
  }
  const size_t base = (size_t)blockIdx.x * (NCH_F + 1);
  cs[base + t] = acc;
  if (t == 0) {
    float s = 0.f;
    for (int l = 0; l < CHUNK_L; l++) s += pw_s[l];
    cs[base + NCH_F] = s;
  }
}

// ---------------------------------------------------------------------------
// scan phase 2: exclusive scan over NCHUNK chunk-sums per (b,k,channel).
// Register-unrolled: 32 independent loads (latency overlapped), register
// prefix sum, independent stores — kills the serial L2 round-trip chain.
// ---------------------------------------------------------------------------
__global__ __launch_bounds__(256) void scan_chunks(float* __restrict__ cs) {
  const int idx = blockIdx.x * 256 + threadIdx.x;
  if (idx >= B_SZC * K_HEADSC * (NCH_F + 1)) return;
  const int c = idx % (NCH_F + 1);
  const int bk = idx / (NCH_F + 1);
  float v[NCHUNK];
#pragma unroll
  for (int ch = 0; ch < NCHUNK; ++ch)
    v[ch] = cs[(size_t)(bk * NCHUNK + ch) * (NCH_F + 1) + c];
  float s = 0.f;
#pragma unroll
  for (int ch = 0; ch < NCHUNK; ++ch) {
    const float x = v[ch];
    v[ch] = s;
    s += x;
  }
#pragma unroll
  for (int ch = 0; ch < NCHUNK; ++ch)
    cs[(size_t)(bk * NCHUNK + ch) * (NCH_F + 1) + c] = v[ch];
}

// ---------------------------------------------------------------------------
// scan phase 3 (FOLDED, 128 threads):
//  A: per-channel cumsum (acc init = chunk offset) -> v (bf16) in LDS (128 ch)
//  B: block sumsq for RMS (x2 fold factor absorbed: /128 instead of /256)
//  C: 64x128 @ 128x32 projection via MFMA; rsq+gate in epilogue
// ---------------------------------------------------------------------------
__global__ __launch_bounds__(128, 4) void scan_apply(
    const ushort_t* __restrict__ xv, const float* __restrict__ pw,
    const ushort_t* __restrict__ gate, const float* __restrict__ theta,
    const float* __restrict__ dlog, const ushort_t* __restrict__ wtp,
    const float* __restrict__ cs, ushort_t* __restrict__ ypre) {
  const int t = threadIdx.x;
  const int chunk = blockIdx.x % NCHUNK;
  const int bk = blockIdx.x / NCHUNK;
  const int k = bk % K_HEADSC;
  const int b = bk / K_HEADSC;
  __shared__ __align__(16) ushort_t xv_s[32 * 68];
  __shared__ __align__(16) float pw_s[CHUNK_L];
  __shared__ __align__(16) float inv_s[CHUNK_L];
  __shared__ __align__(16) ushort_t v_s[CHUNK_L * 136];
  __shared__ __align__(16) float part_s[128];
  __shared__ __align__(16) float rsq_s[CHUNK_L];

  const int l0 = chunk * CHUNK_L;
  const int hld = t & 31, r0 = t >> 5;  // r0 in 0..3
  {
#pragma unroll
    for (int rr = 0; rr < 16; rr++) {
      const int l = r0 + rr * 4;
      xv_s[hld * 68 + l] = xv[(size_t)(b * L_SEQC + l0 + l) * D_MODELC + k * H_DIMC + hld];
    }
  }
  if (t < CHUNK_L)
    pw_s[t] = pw[(size_t)(b * L_SEQC + l0 + t) * K_HEADSC + k];
  const float d0 = dlog[0], d1 = dlog[1], d2 = dlog[2];
  const float mx = fmaxf(d0, fmaxf(d1, d2));
  const float e0 = __expf(d0 - mx), e1 = __expf(d1 - mx), e2 = __expf(d2 - mx);
  const float inv_sum = 1.f / (e0 + e1 + e2);
  const float w0 = e0 * inv_sum, w1 = e1 * inv_sum, w2 = e2 * inv_sum;
  const int cc = t & 63;
  const int h = cc >> 1;
  const bool is_re = (t < 64);
  const float th_rev = theta[k * 128 + h * 4 + (cc & 1)] * INV_2PI;
  const size_t base = (size_t)blockIdx.x * (NCH_F + 1);
  const float off_c = cs[base + t];
  const float den_off = cs[base + NCH_F];
  __syncthreads();
  if (t < 64) {
    float v = pw_s[t];
#pragma unroll
    for (int off = 1; off < 64; off <<= 1) {
      float o = __shfl_up(v, off, 64);
      if (t >= off) v += o;
    }
    inv_s[t] = 1.f / fmaxf(den_off + v, 1e-4f);
  }
  __syncthreads();
  // --- phase A ---
  {
    float acc = off_c;
    const int xoff = h * 68;
    for (int l4 = 0; l4 < CHUNK_L; l4 += 4) {
      ushort4 xr = *(const ushort4*)(xv_s + xoff + l4);
      float4 pw4 = *(const float4*)(pw_s + l4);
      float4 iv4 = *(const float4*)(inv_s + l4);
      const float xs[4] = {bf2f(xr.x), bf2f(xr.y), bf2f(xr.z), bf2f(xr.w)};
      const float ps[4] = {pw4.x, pw4.y, pw4.z, pw4.w};
      const float ivs[4] = {iv4.x, iv4.y, iv4.z, iv4.w};
#pragma unroll
      for (int j = 0; j < 4; j++) {
        const float xx = xs[j];
        const float poly = fmaf(-w2 * xx, xx, fmaf(w1, xx, w0));
        const float phi = xx * th_rev;
        const float tr = is_re ? __builtin_amdgcn_cosf(phi) : __builtin_amdgcn_sinf(phi);
        acc = fmaf(ps[j] * poly, tr, acc);
        v_s[(l4 + j) * 136 + t] = f2bf_fast(acc * ivs[j]);
      }
    }
  }
  __syncthreads();
  // --- phase B --- (2 threads per l; parity-interleaved 8B chunks to spread banks)
  {
    const int l = t >> 1, cg = t & 1;
    const ushort_t* vp = v_s + l * 136;
    float s = 0.f;
#pragma unroll
    for (int ii = 0; ii < 16; ii++) {
      ushort4 a = *(const ushort4*)(vp + (ii * 2 + cg) * 4);
      const float f0 = bf2f(a.x), f1 = bf2f(a.y), f2v = bf2f(a.z), f3 = bf2f(a.w);
      s = fmaf(f0, f0, s);
      s = fmaf(f1, f1, s);
      s = fmaf(f2v, f2v, s);
      s = fmaf(f3, f3, s);
    }
    part_s[t] = s;
  }
  __syncthreads();
  if (t < 64) {
    // fold factor 2: mean over 256 original channels = (2 * sum128) / 256
    rsq_s[t] = rsqrtf((part_s[t * 2] + part_s[t * 2 + 1]) * (1.f / 128.f) + 1e-5f);
  }
  __syncthreads();
  // --- phase C --- (2 waves, each 2 row-tiles x 32 h_out, K=128)
  {
    const int wave = t >> 6, lane = t & 63;
    const int quad = lane >> 4, r16 = lane & 15;
    f32x4 acc0[2] = {}, acc1[2] = {};
    const ushort_t* wb0 = wtp + r16 * NCH_F;
    const ushort_t* wb1 = wtp + (16 + r16) * NCH_F;
#pragma unroll
    for (int kk = 0; kk < 4; kk++) {
      short8 b0 = *(const short8*)(wb0 + kk * 32 + quad * 8);
      short8 b1 = *(const short8*)(wb1 + kk * 32 + quad * 8);
#pragma unroll
      for (int mt = 0; mt < 2; mt++) {
        short8 af = *(const short8*)(v_s + (mt * 32 + wave * 16 + r16) * 136 + kk * 32 + quad * 8);
        acc0[mt] = __builtin_amdgcn_mfma_f32_16x16x32_bf16(af, b0, acc0[mt], 0, 0, 0);
        acc1[mt] = __builtin_amdgcn_mfma_f32_16x16x32_bf16(af, b1, acc1[mt], 0, 0, 0);
      }
    }
#pragma unroll
    for (int mt = 0; mt < 2; mt++) {
#pragma unroll
      for (int r = 0; r < 4; r++) {
        const int l = mt * 32 + wave * 16 + quad * 4 + r;
        const float rs = rsq_s[l];
        const size_t row = (size_t)(b * L_SEQC + l0 + l) * D_MODELC + k * H_DIMC;
        const int h0 = r16, h1 = 16 + r16;
        ypre[row + h0] = f2bf(acc0[mt][r] * rs * bf2f(gate[row + h0]));
        ypre[row + h1] = f2bf(acc1[mt][r] * rs * bf2f(gate[row + h1]));
      }
    }
  }
}

// ---------------------------------------------------------------------------
extern "C" void kernel_launch(void* const* d_in, const int* in_sizes, int n_in,
                              void* d_out, int out_size, void* d_ws, size_t ws_size,
                              hipStream_t stream) {
  const float* x       = (const float*)d_in[0];
  const float* W_in    = (const float*)d_in[1];
  const float* w_conv  = (const float*)d_in[2];
  const float* b_conv  = (const float*)d_in[3];
  const float* theta   = (const float*)d_in[4];
  const float* dec     = (const float*)d_in[5];
  const float* anc     = (const float*)d_in[6];
  const float* score   = (const float*)d_in[7];
  const float* dlog    = (const float*)d_in[8];
  const float* nsc     = (const float*)d_in[9];
  const float* W_re    = (const float*)d_in[10];
  const float* W_im    = (const float*)d_in[11];
  const float* W_out   = (const float*)d_in[12];
  float* out = (float*)d_out;

  char* wsb = (char*)d_ws;
  ushort_t* z    = (ushort_t*)(wsb + 0);          // bf16, 34,078,720 B
  ushort_t* ypre = (ushort_t*)(wsb + 0);          // alias (z dead), 16.8 MB
  float*    cs   = (float*)(wsb + 20971520);      // alias (z dead), 2.1 MB
  ushort_t* xv   = (ushort_t*)(wsb + 68157440);   // 16,777,216
  ushort_t* gate = (ushort_t*)(wsb + 84934656);   // 16,777,216
  float*    pwb  = (float*)(wsb + 101711872);     // 1,048,576
  ushort_t* xb   = (ushort_t*)(wsb + 102760448);  // 16,777,216
  ushort_t* WtI  = (ushort_t*)(wsb + 119537664);  // 4,456,448
  ushort_t* WtO  = (ushort_t*)(wsb + 123994112);  // 2,097,152
  ushort_t* wtp  = (ushort_t*)(wsb + 126091264);  // 8,192 (folded)
  // total <= 126,107,648 B

  dim3 blk(256);
  const int M = B_SZC * L_SEQC;  // 8192

  prep<<<dim3(11408), blk, 0, stream>>>(
      x, W_in, W_out, W_re, W_im, nsc, xb, WtI, WtO, wtp);
  gemm_bf16_bt<true><<<dim3(2176 / 128, M / 128), blk, 0, stream>>>(
      xb, WtI, z, M, D_MODELC, TOTALC);
  conv_act<<<dim3(((B_SZC * L_SEQC / 4) * (TOTALC / 4) + 255) / 256), blk, 0, stream>>>(
      z, w_conv, b_conv, score, dec, anc, xv, gate, pwb);
  // z dead from here; cs/ypre alias its region
  scan_partial<<<dim3(B_SZC * K_HEADSC * NCHUNK), dim3(128), 0, stream>>>(
      xv, pwb, theta, dlog, cs);
  scan_chunks<<<dim3((B_SZC * K_HEADSC * (NCH_F + 1) + 255) / 256), blk, 0, stream>>>(cs);
  scan_apply<<<dim3(B_SZC * K_HEADSC * NCHUNK), dim3(128), 0, stream>>>(
      xv, pwb, gate, theta, dlog, wtp, cs, ypre);
  gemm_bf16_bt<false><<<dim3(D_MODELC / 128, M / 128), blk, 0, stream>>>(
      ypre, WtO, out, M, D_MODELC, D_MODELC);
}

// Round 2
// 239.795 us; speedup vs baseline: 1.0447x; 1.0447x over previous
//
#include <hip/hip_runtime.h>
#include <math.h>

#define D_MODELC 1024
#define K_HEADSC 32
#define ANCHORC 4
#define M_THETAC 4
#define H_DIMC 32
#define TOTALC 2080
#define B_SZC 4
#define L_SEQC 2048
#define NCHUNK 32
#define CHUNK_L (L_SEQC / NCHUNK)  // 64
#define INV_2PI 0.15915494309189535f
// Folded channels: theta grid is antisymmetric (theta[3-m] == -theta[m]),
// so re channels (h,m)/(h,3-m) are equal and im channels negated. We keep
// m in {0,1} only (NCH_F = 2*H*2 = 128) and fold the pair weights into wtp.
#define NCH_F 128

typedef unsigned short ushort_t;
typedef __attribute__((ext_vector_type(8))) short short8;
typedef __attribute__((ext_vector_type(4))) float f32x4;

__device__ __forceinline__ ushort_t f2bf(float f) {
  union { float f; unsigned u; } v; v.f = f;
  unsigned u = v.u;
  return (ushort_t)((u + 0x7fffu + ((u >> 16) & 1u)) >> 16);
}
__device__ __forceinline__ ushort_t f2bf_fast(float f) {
  union { float f; unsigned u; } v; v.f = f;
  return (ushort_t)((v.u + 0x8000u) >> 16);
}
__device__ __forceinline__ float bf2f(ushort_t b) {
  union { unsigned u; float f; } v; v.u = ((unsigned)b) << 16;
  return v.f;
}

// ---------------------------------------------------------------------------
// prep: fused x->bf16 cast, W_in^T, W_out^T, folded wt_pack (block-range)
// ---------------------------------------------------------------------------
__global__ __launch_bounds__(256) void prep(
    const float* __restrict__ x, const float* __restrict__ W_in,
    const float* __restrict__ W_out, const float* __restrict__ W_re,
    const float* __restrict__ W_im, const float* __restrict__ nsc,
    ushort_t* __restrict__ xb, ushort_t* __restrict__ WtI,
    ushort_t* __restrict__ WtO, ushort_t* __restrict__ wtp) {
  __shared__ float tile[32][33];
  const int bid = blockIdx.x;
  const int t = threadIdx.x;
  if (bid < 8192) {
    const int i = (bid * 256 + t) * 4;
    float4 v = *(const float4*)(x + i);
    ushort4 o = {f2bf(v.x), f2bf(v.y), f2bf(v.z), f2bf(v.w)};
    *(ushort4*)(xb + i) = o;
    return;
  }
  const float* W;
  ushort_t* Wt;
  int N, bx, by;
  if (bid < 10368) {
    const int bb = bid - 8192;
    W = W_in; Wt = WtI; N = TOTALC;
    bx = bb % 68; by = bb / 68;
  } else if (bid < 11392) {
    const int bb = bid - 10368;
    W = W_out; Wt = WtO; N = D_MODELC;
    bx = bb % 32; by = bb / 32;
  } else {
    // folded weight pack: 32 h_out x 128 folded channels
    const int i = (bid - 11392) * 256 + t;  // 0..4095
    const int h_out = i & 31;
    const int chp = i >> 5;                 // 0..127
    const bool isre = chp < 64;
    const int cc = chp & 63;
    const int hh = cc >> 1, mm = cc & 1;
    const int c1 = hh * 4 + mm;
    const int c2 = hh * 4 + (3 - mm);
    float wv;
    if (isre)
      wv = nsc[c1] * W_re[c1 * 32 + h_out] + nsc[c2] * W_re[c2 * 32 + h_out];
    else
      wv = nsc[128 + c1] * W_im[c1 * 32 + h_out] - nsc[128 + c2] * W_im[c2 * 32 + h_out];
    wtp[h_out * NCH_F + chp] = f2bf(wv);
    return;
  }
  const int K = D_MODELC;
  const int n0 = bx * 32, k0 = by * 32;
  const int tx = t & 31, ty = t >> 5;
#pragma unroll
  for (int i = 0; i < 4; i++) {
    const int kk = ty + i * 8;
    const int n = n0 + tx;
    tile[kk][tx] = (n < N) ? W[(size_t)(k0 + kk) * N + n] : 0.f;
  }
  __syncthreads();
#pragma unroll
  for (int i = 0; i < 4; i++) {
    const int nn = ty + i * 8;
    Wt[(size_t)(n0 + nn) * K + k0 + tx] = f2bf(tile[tx][nn]);
  }
}

// ---------------------------------------------------------------------------
// gemm_conv: z = xb @ WtI^T fused with causal depthwise conv + activations.
// 128x128 tile, BK=64, XOR-swizzled LDS. Ghost band: waves 0/1 compute an
// extra 16-row MFMA band (rows m0-16..m0-1) so conv taps m0-3..m0-1 are
// available in-tile. z never touches HBM: acc -> bf16 LDS (col-major,
// stride 132) -> conv -> xv/gate/pw. T1 XCD swizzle (1088 = 8*136).
// ---------------------------------------------------------------------------
__global__ __launch_bounds__(256) void gemm_conv(
    const ushort_t* __restrict__ A, const ushort_t* __restrict__ Bt,
    const float* __restrict__ wconv, const float* __restrict__ bconv,
    const float* __restrict__ score_scale, const float* __restrict__ dec_slopes,
    const float* __restrict__ anc_slopes, ushort_t* __restrict__ xv,
    ushort_t* __restrict__ gate, float* __restrict__ pw) {
  __shared__ ushort_t smem[17408];
  ushort_t* As = smem;           // 128x64
  ushort_t* Bs = smem + 8192;    // 128x64
  ushort_t* Ag = smem + 16384;   // 16x64 ghost band
  ushort_t* z_s = smem;          // epilogue alias: [128 col][132 row], zr = lr+4

  const int t = threadIdx.x;
  const int wave = t >> 6, lane = t & 63;
  // XCD-aware bijective swizzle: each XCD gets 8 contiguous m-panels
  const int lin = blockIdx.y * 17 + blockIdx.x;
  const int nid = (lin & 7) * 136 + (lin >> 3);
  const int bx = nid % 17, by = nid / 17;
  const int m0 = by * 128, n0 = bx * 128;
  const bool batch_start = (by & 15) == 0;
  const int m0g = (by == 0) ? 0 : m0 - 16;

  const int m0w = (wave >> 1) * 64, n0w = (wave & 1) * 64;
  const int quad = lane >> 4, r16 = lane & 15;
  const int srow = lane >> 3;
  const int scol = ((lane & 7) ^ srow) * 8;

  f32x4 acc[4][4] = {};
  f32x4 accg[4] = {};

  for (int k0 = 0; k0 < D_MODELC; k0 += 64) {
    __syncthreads();
#pragma unroll
    for (int i = 0; i < 4; i++) {
      const int seg = wave * 4 + i;
      const int row = seg * 8 + srow;
      const ushort_t* gpA = A + (size_t)(m0 + row) * D_MODELC + k0 + scol;
      const ushort_t* gpB = Bt + (size_t)(n0 + row) * D_MODELC + k0 + scol;
      __builtin_amdgcn_global_load_lds(
          (const __attribute__((address_space(1))) void*)gpA,
          (__attribute__((address_space(3))) void*)(As + seg * 512), 16, 0, 0);
      __builtin_amdgcn_global_load_lds(
          (const __attribute__((address_space(1))) void*)gpB,
          (__attribute__((address_space(3))) void*)(Bs + seg * 512), 16, 0, 0);
    }
    if (wave < 2) {
      const int row = wave * 8 + srow;
      const ushort_t* gpG = A + (size_t)(m0g + row) * D_MODELC + k0 + scol;
      __builtin_amdgcn_global_load_lds(
          (const __attribute__((address_space(1))) void*)gpG,
          (__attribute__((address_space(3))) void*)(Ag + wave * 512), 16, 0, 0);
    }
    __syncthreads();
#pragma unroll
    for (int kk = 0; kk < 2; kk++) {
      const int swz = ((kk * 4 + quad) ^ (r16 & 7)) * 8;
      short8 af[4], bfv[4];
#pragma unroll
      for (int i = 0; i < 4; i++)
        af[i] = *(const short8*)(As + (m0w + i * 16 + r16) * 64 + swz);
#pragma unroll
      for (int j = 0; j < 4; j++)
        bfv[j] = *(const short8*)(Bs + (n0w + j * 16 + r16) * 64 + swz);
#pragma unroll
      for (int i = 0; i < 4; i++)
#pragma unroll
        for (int j = 0; j < 4; j++)
          acc[i][j] = __builtin_amdgcn_mfma_f32_16x16x32_bf16(
              af[i], bfv[j], acc[i][j], 0, 0, 0);
      if (wave < 2) {
        short8 ag = *(const short8*)(Ag + r16 * 64 + swz);
#pragma unroll
        for (int j = 0; j < 4; j++)
          accg[j] = __builtin_amdgcn_mfma_f32_16x16x32_bf16(
              ag, bfv[j], accg[j], 0, 0, 0);
      }
    }
  }

  // ---- epilogue: z tile -> LDS (bf16, transposed col-major) ----
  __syncthreads();
#pragma unroll
  for (int i = 0; i < 4; i++) {
#pragma unroll
    for (int j = 0; j < 4; j++) {
      ushort4 o = {f2bf(acc[i][j][0]), f2bf(acc[i][j][1]),
                   f2bf(acc[i][j][2]), f2bf(acc[i][j][3])};
      *(ushort4*)(z_s + (n0w + j * 16 + r16) * 132 +
                  (m0w + i * 16 + quad * 4 + 4)) = o;
    }
  }
  if (wave < 2 && quad == 3) {
    // ghost rows: lr_g = 12+r (r=1..3) -> zr = r; zero at batch boundary
#pragma unroll
    for (int j = 0; j < 4; j++) {
#pragma unroll
      for (int r = 1; r < 4; r++) {
        z_s[(n0w + j * 16 + r16) * 132 + r] =
            batch_start ? (ushort_t)0 : f2bf(accg[j][r]);
      }
    }
  }
  __syncthreads();

  // ---- conv + activation from LDS strips ----
  if (bx < 16) {
    const int c = t & 127, half = t >> 7;
    const int ch = n0 + c;
    const float w0c = wconv[0 * TOTALC + ch], w1c = wconv[1 * TOTALC + ch];
    const float w2c = wconv[2 * TOTALC + ch], w3c = wconv[3 * TOTALC + ch];
    const float bcv = bconv[ch];
    const ushort_t* col = z_s + c * 132;
#pragma unroll
    for (int sc = 0; sc < 2; sc++) {
      const int base = half * 64 + sc * 32;
      float zf[36];
#pragma unroll
      for (int q8 = 0; q8 < 9; q8++) {
        ushort4 a = *(const ushort4*)(col + base + q8 * 4);
        zf[q8 * 4 + 0] = bf2f(a.x); zf[q8 * 4 + 1] = bf2f(a.y);
        zf[q8 * 4 + 2] = bf2f(a.z); zf[q8 * 4 + 3] = bf2f(a.w);
      }
#pragma unroll
      for (int rl = 0; rl < 32; rl++) {
        float o = fmaf(w3c, zf[rl + 4], fmaf(w2c, zf[rl + 3],
                  fmaf(w1c, zf[rl + 2], fmaf(w0c, zf[rl + 1], bcv))));
        const int gm = m0 + base + rl;
        if (bx < 8) {
          xv[(size_t)gm * D_MODELC + ch] = f2bf(o);
        } else {
          gate[(size_t)gm * D_MODELC + (ch - D_MODELC)] =
              f2bf(o / (1.f + __expf(-o)));
        }
      }
    }
  } else {
    // scores tile: cols 2048..2079 -> pw; cols >=2080 are padding (ignored)
    const int k = t & 31, rseg = t >> 5;
    const int ch = 2 * D_MODELC + k;
    const float w0c = wconv[0 * TOTALC + ch], w1c = wconv[1 * TOTALC + ch];
    const float w2c = wconv[2 * TOTALC + ch], w3c = wconv[3 * TOTALC + ch];
    const float bcv = bconv[ch];
    const float ssv = score_scale[k];
    const bool dec_h = k < (K_HEADSC - ANCHORC);
    const float sl = dec_h ? log1pf(__expf(dec_slopes[k]))
                           : log1pf(__expf(anc_slopes[k - (K_HEADSC - ANCHORC)]));
    const ushort_t* col = z_s + k * 132;
    const int base = rseg * 16;
    float zf[20];
#pragma unroll
    for (int q5 = 0; q5 < 5; q5++) {
      ushort4 a = *(const ushort4*)(col + base + q5 * 4);
      zf[q5 * 4 + 0] = bf2f(a.x); zf[q5 * 4 + 1] = bf2f(a.y);
      zf[q5 * 4 + 2] = bf2f(a.z); zf[q5 * 4 + 3] = bf2f(a.w);
    }
#pragma unroll
    for (int rl = 0; rl < 16; rl++) {
      float o = fmaf(w3c, zf[rl + 4], fmaf(w2c, zf[rl + 3],
                fmaf(w1c, zf[rl + 2], fmaf(w0c, zf[rl + 1], bcv))));
      const int gm = m0 + base + rl;
      const int l = gm & (L_SEQC - 1);
      const float dist = dec_h ? (float)(L_SEQC - 1 - l) : (float)l;
      const float sv = fminf(fmaxf(ssv * o, -20.f), 20.f);
      pw[(size_t)gm * K_HEADSC + k] = __expf(sv) * __expf(-sl * dist);
    }
  }
}

// ---------------------------------------------------------------------------
// bf16 MFMA GEMM (second projection): C[M,Nout] = A[M,K] @ Bt[N,K]^T
// BK=64, XOR-swizzled LDS + T1 XCD swizzle.
// ---------------------------------------------------------------------------
template <bool OBF16>
__global__ __launch_bounds__(256) void gemm_bf16_bt(
    const ushort_t* __restrict__ A, const ushort_t* __restrict__ Bt,
    void* __restrict__ Cv, int M, int K, int Nout) {
  __shared__ ushort_t As[128 * 64];
  __shared__ ushort_t Bs[128 * 64];
  const int t = threadIdx.x;
  const int wave = t >> 6, lane = t & 63;
  // XCD-aware bijective swizzle (requires nwg % 8 == 0)
  const int nwg = gridDim.x * gridDim.y;
  const int lin = blockIdx.y * gridDim.x + blockIdx.x;
  const int nid = (lin & 7) * (nwg >> 3) + (lin >> 3);
  const int bxs = nid % gridDim.x, bys = nid / gridDim.x;
  const int m0 = bys * 128, n0 = bxs * 128;
  const int m0w = (wave >> 1) * 64, n0w = (wave & 1) * 64;
  const int quad = lane >> 4, r16 = lane & 15;
  const int srow = lane >> 3;
  const int scol = ((lane & 7) ^ srow) * 8;

  f32x4 acc[4][4] = {};

  for (int k0 = 0; k0 < K; k0 += 64) {
    __syncthreads();
#pragma unroll
    for (int i = 0; i < 4; i++) {
      const int seg = wave * 4 + i;
      const int row = seg * 8 + srow;
      const ushort_t* gpA = A + (size_t)(m0 + row) * K + k0 + scol;
      const ushort_t* gpB = Bt + (size_t)(n0 + row) * K + k0 + scol;
      __builtin_amdgcn_global_load_lds(
          (const __attribute__((address_space(1))) void*)gpA,
          (__attribute__((address_space(3))) void*)(As + seg * 512), 16, 0, 0);
      __builtin_amdgcn_global_load_lds(
          (const __attribute__((address_space(1))) void*)gpB,
          (__attribute__((address_space(3))) void*)(Bs + seg * 512), 16, 0, 0);
    }
    __syncthreads();
#pragma unroll
    for (int kk = 0; kk < 2; kk++) {
      const int swz = ((kk * 4 + quad) ^ (r16 & 7)) * 8;
      short8 af[4], bfv[4];
#pragma unroll
      for (int i = 0; i < 4; i++)
        af[i] = *(const short8*)(As + (m0w + i * 16 + r16) * 64 + swz);
#pragma unroll
      for (int j = 0; j < 4; j++)
        bfv[j] = *(const short8*)(Bs + (n0w + j * 16 + r16) * 64 + swz);
#pragma unroll
      for (int i = 0; i < 4; i++)
#pragma unroll
        for (int j = 0; j < 4; j++)
          acc[i][j] = __builtin_amdgcn_mfma_f32_16x16x32_bf16(
              af[i], bfv[j], acc[i][j], 0, 0, 0);
    }
  }

#pragma unroll
  for (int i = 0; i < 4; i++) {
#pragma unroll
    for (int j = 0; j < 4; j++) {
      const int n = n0 + n0w + j * 16 + r16;
      if (n >= Nout) continue;
#pragma unroll
      for (int r = 0; r < 4; r++) {
        const int m = m0 + m0w + i * 16 + quad * 4 + r;
        if constexpr (OBF16) {
          ((ushort_t*)Cv)[(size_t)m * Nout + n] = f2bf(acc[i][j][r]);
        } else {
          ((float*)Cv)[(size_t)m * Nout + n] = acc[i][j][r];
        }
      }
    }
  }
}

// ---------------------------------------------------------------------------
// scan phase 1 (FOLDED): per (b,k,chunk) sums of pw*poly*cos/sin over the
// 128 folded channels (m in {0,1} only) + den. 128 threads/block.
// ---------------------------------------------------------------------------
__global__ __launch_bounds__(128) void scan_partial(
    const ushort_t* __restrict__ xv, const float* __restrict__ pw,
    const float* __restrict__ theta, const float* __restrict__ dlog,
    float* __restrict__ cs) {
  const int t = threadIdx.x;
  const int chunk = blockIdx.x % NCHUNK;
  const int bk = blockIdx.x / NCHUNK;
  const int k = bk % K_HEADSC;
  const int b = bk / K_HEADSC;
  __shared__ __align__(16) ushort_t xv_s[32 * 68];
  __shared__ __align__(16) float pp_s[32 * 68];
  __shared__ __align__(16) float pw_s[CHUNK_L];
  const int l0 = chunk * CHUNK_L;
  const int hld = t & 31, r0 = t >> 5;  // r0 in 0..3
  {
#pragma unroll
    for (int rr = 0; rr < 16; rr++) {
      const int l = r0 + rr * 4;
      xv_s[hld * 68 + l] = xv[(size_t)(b * L_SEQC + l0 + l) * D_MODELC + k * H_DIMC + hld];
    }
  }
  if (t < CHUNK_L)
    pw_s[t] = pw[(size_t)(b * L_SEQC + l0 + t) * K_HEADSC + k];
  const float d0 = dlog[0], d1 = dlog[1], d2 = dlog[2];
  const float mx = fmaxf(d0, fmaxf(d1, d2));
  const float e0 = __expf(d0 - mx), e1 = __expf(d1 - mx), e2 = __expf(d2 - mx);
  const float inv_sum = 1.f / (e0 + e1 + e2);
  const float w0 = e0 * inv_sum, w1 = e1 * inv_sum, w2 = e2 * inv_sum;
  const int cc = t & 63;
  const int h = cc >> 1;
  const bool is_re = (t < 64);
  const float th_rev = theta[k * 128 + h * 4 + (cc & 1)] * INV_2PI;
  __syncthreads();
  {
#pragma unroll
    for (int rr = 0; rr < 16; rr++) {
      const int l = r0 + rr * 4;
      const float xx = bf2f(xv_s[hld * 68 + l]);
      const float poly = fmaf(-w2 * xx, xx, fmaf(w1, xx, w0));
      pp_s[hld * 68 + l] = pw_s[l] * poly;
    }
  }
  __syncthreads();
  float acc = 0.f;
  const int xoff = h * 68;
  for (int l4 = 0; l4 < CHUNK_L; l4 += 4) {
    ushort4 xr = *(const ushort4*)(xv_s + xoff + l4);
    float4 pr = *(const float4*)(pp_s + xoff + l4);
    const float xs[4] = {bf2f(xr.x), bf2f(xr.y), bf2f(xr.z), bf2f(xr.w)};
    const float ps[4] = {pr.x, pr.y, pr.z, pr.w};
#pragma unroll
    for (int j = 0; j < 4; j++) {
      const float phi = xs[j] * th_rev;
      const float tr = is_re ? __builtin_amdgcn_cosf(phi) : __builtin_amdgcn_sinf(phi);
      acc = fmaf(ps[j], tr, acc);
    }
  }
  const size_t base = (size_t)blockIdx.x * (NCH_F + 1);
  cs[base + t] = acc;
  if (t == 0) {
    float s = 0.f;
    for (int l = 0; l < CHUNK_L; l++) s += pw_s[l];
    cs[base + NCH_F] = s;
  }
}

// ---------------------------------------------------------------------------
// scan phase 2: exclusive scan over NCHUNK chunk-sums per (b,k,channel).
// Register-unrolled: 32 independent loads, register prefix, stores.
// ---------------------------------------------------------------------------
__global__ __launch_bounds__(256) void scan_chunks(float* __restrict__ cs) {
  const int idx = blockIdx.x * 256 + threadIdx.x;
  if (idx >= B_SZC * K_HEADSC * (NCH_F + 1)) return;
  const int c = idx % (NCH_F + 1);
  const int bk = idx / (NCH_F + 1);
  float v[NCHUNK];
#pragma unroll
  for (int ch = 0; ch < NCHUNK; ++ch)
    v[ch] = cs[(size_t)(bk * NCHUNK + ch) * (NCH_F + 1) + c];
  float s = 0.f;
#pragma unroll
  for (int ch = 0; ch < NCHUNK; ++ch) {
    const float x = v[ch];
    v[ch] = s;
    s += x;
  }
#pragma unroll
  for (int ch = 0; ch < NCHUNK; ++ch)
    cs[(size_t)(bk * NCHUNK + ch) * (NCH_F + 1) + c] = v[ch];
}

// ---------------------------------------------------------------------------
// scan phase 3 (FOLDED, 128 threads):
//  A: per-channel cumsum (acc init = chunk offset) -> v (bf16) in LDS (128 ch)
//  B: block sumsq for RMS (x2 fold factor: /128)
//  C: 64x128 @ 128x32 projection via MFMA; rsq+gate in epilogue
// ---------------------------------------------------------------------------
__global__ __launch_bounds__(128, 4) void scan_apply(
    const ushort_t* __restrict__ xv, const float* __restrict__ pw,
    const ushort_t* __restrict__ gate, const float* __restrict__ theta,
    const float* __restrict__ dlog, const ushort_t* __restrict__ wtp,
    const float* __restrict__ cs, ushort_t* __restrict__ ypre) {
  const int t = threadIdx.x;
  const int chunk = blockIdx.x % NCHUNK;
  const int bk = blockIdx.x / NCHUNK;
  const int k = bk % K_HEADSC;
  const int b = bk / K_HEADSC;
  __shared__ __align__(16) ushort_t xv_s[32 * 68];
  __shared__ __align__(16) float pw_s[CHUNK_L];
  __shared__ __align__(16) float inv_s[CHUNK_L];
  __shared__ __align__(16) ushort_t v_s[CHUNK_L * 136];
  __shared__ __align__(16) float part_s[128];
  __shared__ __align__(16) float rsq_s[CHUNK_L];

  const int l0 = chunk * CHUNK_L;
  const int hld = t & 31, r0 = t >> 5;  // r0 in 0..3
  {
#pragma unroll
    for (int rr = 0; rr < 16; rr++) {
      const int l = r0 + rr * 4;
      xv_s[hld * 68 + l] = xv[(size_t)(b * L_SEQC + l0 + l) * D_MODELC + k * H_DIMC + hld];
    }
  }
  if (t < CHUNK_L)
    pw_s[t] = pw[(size_t)(b * L_SEQC + l0 + t) * K_HEADSC + k];
  const float d0 = dlog[0], d1 = dlog[1], d2 = dlog[2];
  const float mx = fmaxf(d0, fmaxf(d1, d2));
  const float e0 = __expf(d0 - mx), e1 = __expf(d1 - mx), e2 = __expf(d2 - mx);
  const float inv_sum = 1.f / (e0 + e1 + e2);
  const float w0 = e0 * inv_sum, w1 = e1 * inv_sum, w2 = e2 * inv_sum;
  const int cc = t & 63;
  const int h = cc >> 1;
  const bool is_re = (t < 64);
  const float th_rev = theta[k * 128 + h * 4 + (cc & 1)] * INV_2PI;
  const size_t base = (size_t)blockIdx.x * (NCH_F + 1);
  const float off_c = cs[base + t];
  const float den_off = cs[base + NCH_F];
  __syncthreads();
  if (t < 64) {
    float v = pw_s[t];
#pragma unroll
    for (int off = 1; off < 64; off <<= 1) {
      float o = __shfl_up(v, off, 64);
      if (t >= off) v += o;
    }
    inv_s[t] = 1.f / fmaxf(den_off + v, 1e-4f);
  }
  __syncthreads();
  // --- phase A ---
  {
    float acc = off_c;
    const int xoff = h * 68;
    for (int l4 = 0; l4 < CHUNK_L; l4 += 4) {
      ushort4 xr = *(const ushort4*)(xv_s + xoff + l4);
      float4 pw4 = *(const float4*)(pw_s + l4);
      float4 iv4 = *(const float4*)(inv_s + l4);
      const float xs[4] = {bf2f(xr.x), bf2f(xr.y), bf2f(xr.z), bf2f(xr.w)};
      const float ps[4] = {pw4.x, pw4.y, pw4.z, pw4.w};
      const float ivs[4] = {iv4.x, iv4.y, iv4.z, iv4.w};
#pragma unroll
      for (int j = 0; j < 4; j++) {
        const float xx = xs[j];
        const float poly = fmaf(-w2 * xx, xx, fmaf(w1, xx, w0));
        const float phi = xx * th_rev;
        const float tr = is_re ? __builtin_amdgcn_cosf(phi) : __builtin_amdgcn_sinf(phi);
        acc = fmaf(ps[j] * poly, tr, acc);
        v_s[(l4 + j) * 136 + t] = f2bf_fast(acc * ivs[j]);
      }
    }
  }
  __syncthreads();
  // --- phase B ---
  {
    const int l = t >> 1, cg = t & 1;
    const ushort_t* vp = v_s + l * 136;
    float s = 0.f;
#pragma unroll
    for (int ii = 0; ii < 16; ii++) {
      ushort4 a = *(const ushort4*)(vp + (ii * 2 + cg) * 4);
      const float f0 = bf2f(a.x), f1 = bf2f(a.y), f2v = bf2f(a.z), f3 = bf2f(a.w);
      s = fmaf(f0, f0, s);
      s = fmaf(f1, f1, s);
      s = fmaf(f2v, f2v, s);
      s = fmaf(f3, f3, s);
    }
    part_s[t] = s;
  }
  __syncthreads();
  if (t < 64) {
    rsq_s[t] = rsqrtf((part_s[t * 2] + part_s[t * 2 + 1]) * (1.f / 128.f) + 1e-5f);
  }
  __syncthreads();
  // --- phase C ---
  {
    const int wave = t >> 6, lane = t & 63;
    const int quad = lane >> 4, r16 = lane & 15;
    f32x4 acc0[2] = {}, acc1[2] = {};
    const ushort_t* wb0 = wtp + r16 * NCH_F;
    const ushort_t* wb1 = wtp + (16 + r16) * NCH_F;
#pragma unroll
    for (int kk = 0; kk < 4; kk++) {
      short8 b0 = *(const short8*)(wb0 + kk * 32 + quad * 8);
      short8 b1 = *(const short8*)(wb1 + kk * 32 + quad * 8);
#pragma unroll
      for (int mt = 0; mt < 2; mt++) {
        short8 af = *(const short8*)(v_s + (mt * 32 + wave * 16 + r16) * 136 + kk * 32 + quad * 8);
        acc0[mt] = __builtin_amdgcn_mfma_f32_16x16x32_bf16(af, b0, acc0[mt], 0, 0, 0);
        acc1[mt] = __builtin_amdgcn_mfma_f32_16x16x32_bf16(af, b1, acc1[mt], 0, 0, 0);
      }
    }
#pragma unroll
    for (int mt = 0; mt < 2; mt++) {
#pragma unroll
      for (int r = 0; r < 4; r++) {
        const int l = mt * 32 + wave * 16 + quad * 4 + r;
        const float rs = rsq_s[l];
        const size_t row = (size_t)(b * L_SEQC + l0 + l) * D_MODELC + k * H_DIMC;
        const int h0 = r16, h1 = 16 + r16;
        ypre[row + h0] = f2bf(acc0[mt][r] * rs * bf2f(gate[row + h0]));
        ypre[row + h1] = f2bf(acc1[mt][r] * rs * bf2f(gate[row + h1]));
      }
    }
  }
}

// ---------------------------------------------------------------------------
extern "C" void kernel_launch(void* const* d_in, const int* in_sizes, int n_in,
                              void* d_out, int out_size, void* d_ws, size_t ws_size,
                              hipStream_t stream) {
  const float* x       = (const float*)d_in[0];
  const float* W_in    = (const float*)d_in[1];
  const float* w_conv  = (const float*)d_in[2];
  const float* b_conv  = (const float*)d_in[3];
  const float* theta   = (const float*)d_in[4];
  const float* dec     = (const float*)d_in[5];
  const float* anc     = (const float*)d_in[6];
  const float* score   = (const float*)d_in[7];
  const float* dlog    = (const float*)d_in[8];
  const float* nsc     = (const float*)d_in[9];
  const float* W_re    = (const float*)d_in[10];
  const float* W_im    = (const float*)d_in[11];
  const float* W_out   = (const float*)d_in[12];
  float* out = (float*)d_out;

  char* wsb = (char*)d_ws;
  ushort_t* ypre = (ushort_t*)(wsb + 0);          // 16.8 MB
  float*    cs   = (float*)(wsb + 20971520);      // 2.1 MB
  ushort_t* xv   = (ushort_t*)(wsb + 68157440);   // 16,777,216
  ushort_t* gate = (ushort_t*)(wsb + 84934656);   // 16,777,216
  float*    pwb  = (float*)(wsb + 101711872);     // 1,048,576
  ushort_t* xb   = (ushort_t*)(wsb + 102760448);  // 16,777,216
  ushort_t* WtI  = (ushort_t*)(wsb + 119537664);  // 4,456,448
  ushort_t* WtO  = (ushort_t*)(wsb + 123994112);  // 2,097,152
  ushort_t* wtp  = (ushort_t*)(wsb + 126091264);  // 8,192 (folded)
  // total <= 126,107,648 B

  dim3 blk(256);
  const int M = B_SZC * L_SEQC;  // 8192

  prep<<<dim3(11408), blk, 0, stream>>>(
      x, W_in, W_out, W_re, W_im, nsc, xb, WtI, WtO, wtp);
  gemm_conv<<<dim3(17, M / 128), blk, 0, stream>>>(
      xb, WtI, w_conv, b_conv, score, dec, anc, xv, gate, pwb);
  scan_partial<<<dim3(B_SZC * K_HEADSC * NCHUNK), dim3(128), 0, stream>>>(
      xv, pwb, theta, dlog, cs);
  scan_chunks<<<dim3((B_SZC * K_HEADSC * (NCH_F + 1) + 255) / 256), blk, 0, stream>>>(cs);
  scan_apply<<<dim3(B_SZC * K_HEADSC * NCHUNK), dim3(128), 0, stream>>>(
      xv, pwb, gate, theta, dlog, wtp, cs, ypre);
  gemm_bf16_bt<false><<<dim3(D_MODELC / 128, M / 128), blk, 0, stream>>>(
      ypre, WtO, out, M, D_MODELC, D_MODELC);
}